// Round 11
// baseline (197.206 us; speedup 1.0000x reference)
//
#include <hip/hip_runtime.h>

typedef __attribute__((ext_vector_type(8))) short bf16x8;
typedef __attribute__((ext_vector_type(4))) float f32x4;

#define CAPB 5632   // per-bucket capacity (mean E/NB ~= 4092, sd ~64)
#define NBMAX 512   // supports n <= 131072

static __device__ __forceinline__ unsigned short f2bf(float f) {
    unsigned u = __float_as_uint(f);
    unsigned r = (u + 0x7fff + ((u >> 16) & 1)) >> 16;  // RNE
    return (unsigned short)r;
}
static __device__ __forceinline__ float bfu_lo(unsigned v) { return __uint_as_float(v << 16); }
static __device__ __forceinline__ float bfu_hi(unsigned v) { return __uint_as_float(v & 0xffff0000u); }
static __device__ __forceinline__ unsigned packbf(float a, float b) {
    return (unsigned)f2bf(a) | ((unsigned)f2bf(b) << 16);
}

static __device__ __forceinline__ bf16x8 cvt8(float4 u0, float4 u1) {
    bf16x8 r;
    r[0] = (short)f2bf(u0.x); r[1] = (short)f2bf(u0.y);
    r[2] = (short)f2bf(u0.z); r[3] = (short)f2bf(u0.w);
    r[4] = (short)f2bf(u1.x); r[5] = (short)f2bf(u1.y);
    r[6] = (short)f2bf(u1.z); r[7] = (short)f2bf(u1.w);
    return r;
}

__global__ void k_zero_int(int* __restrict__ p, int n) {
    int i = blockIdx.x * blockDim.x + threadIdx.x;
    if (i < n) p[i] = 0;
}

// ---------------- Pass A: bucket edges by dst>>8; 32-bit packed (r<<8 | c&255) ----------
__global__ __launch_bounds__(256) void k_passA(const int* __restrict__ row,
                                               const int* __restrict__ col,
                                               int* __restrict__ gcnt,
                                               unsigned* __restrict__ packed,
                                               int E, int NB) {
    __shared__ int lcnt[NBMAX];
    __shared__ int lbase[NBMAX];
    __shared__ int lcur[NBMAX];
    __shared__ int gbaseS[NBMAX];
    __shared__ unsigned stage[4096];
    __shared__ unsigned short stageb[4096];
    __shared__ int s[256];

    int tid = threadIdx.x;
    int t0 = blockIdx.x * 4096;
    int total = min(4096, E - t0);

    for (int b = tid; b < NBMAX; b += 256) { lcnt[b] = 0; lcur[b] = 0; }
    __syncthreads();

    int er[16], ec[16];
#pragma unroll
    for (int j = 0; j < 16; ++j) {
        int e = t0 + j * 256 + tid;
        if (e < E) {
            er[j] = row[e];
            ec[j] = col[e];
            atomicAdd(&lcnt[ec[j] >> 8], 1);
        }
    }
    __syncthreads();

    int c0 = lcnt[2 * tid], c1 = lcnt[2 * tid + 1];
    int p = c0 + c1;
    s[tid] = p;
    __syncthreads();
    for (int off = 1; off < 256; off <<= 1) {
        int t = (tid >= off) ? s[tid - off] : 0;
        __syncthreads();
        s[tid] += t;
        __syncthreads();
    }
    int ebase = s[tid] - p;
    lbase[2 * tid] = ebase;
    lbase[2 * tid + 1] = ebase + c0;
    __syncthreads();

    for (int b = tid; b < NB; b += 256) {
        int lc = lcnt[b];
        if (lc > 0) gbaseS[b] = atomicAdd(&gcnt[b], lc);
    }
    __syncthreads();

#pragma unroll
    for (int j = 0; j < 16; ++j) {
        int e = t0 + j * 256 + tid;
        if (e < E) {
            int b = ec[j] >> 8;
            int pos = lbase[b] + atomicAdd(&lcur[b], 1);
            stage[pos] = ((unsigned)er[j] << 8) | ((unsigned)ec[j] & 255u);
            stageb[pos] = (unsigned short)b;
        }
    }
    __syncthreads();

    for (int j = tid; j < total; j += 256) {
        int b = stageb[j];
        packed[(size_t)b * CAPB + gbaseS[b] + (j - lbase[b])] = stage[j];
    }
}

__global__ void k_bscan(const int* __restrict__ gcnt, int* __restrict__ gbase,
                        int* __restrict__ indptr, int n, int E, int NB) {
    __shared__ int s[512];
    int tid = threadIdx.x;
    int v = (tid < NB) ? gcnt[tid] : 0;
    s[tid] = v;
    __syncthreads();
    for (int off = 1; off < 512; off <<= 1) {
        int t = (tid >= off) ? s[tid - off] : 0;
        __syncthreads();
        s[tid] += t;
        __syncthreads();
    }
    if (tid < NB) gbase[tid] = s[tid] - v;
    if (tid == 0) indptr[n] = E;
}

// ---------------- Pass B: per-bucket CSR finalize ----------------
__global__ __launch_bounds__(256) void k_passB(const unsigned* __restrict__ packed,
                                               const int* __restrict__ gcnt,
                                               const int* __restrict__ gbase,
                                               int* __restrict__ indptr,
                                               float* __restrict__ dinv,
                                               int* __restrict__ srcidx, int n) {
    __shared__ int ncnt[256];
    __shared__ int nbase[256];
    __shared__ int srow[CAPB];

    int b = blockIdx.x;
    int tid = threadIdx.x;
    int nodeBase = b << 8;
    int cntE = min(gcnt[b], CAPB);
    int base = gbase[b];
    size_t pb = (size_t)b * CAPB;

    ncnt[tid] = 0;
    __syncthreads();

    for (int j = tid; j < cntE; j += 256) {
        unsigned e = packed[pb + j];
        atomicAdd(&ncnt[e & 255u], 1);
    }
    __syncthreads();

    int v = ncnt[tid];
    nbase[tid] = v;
    __syncthreads();
    for (int off = 1; off < 256; off <<= 1) {
        int t = (tid >= off) ? nbase[tid - off] : 0;
        __syncthreads();
        nbase[tid] += t;
        __syncthreads();
    }
    int excl = nbase[tid] - v;
    __syncthreads();
    nbase[tid] = excl;

    int node = nodeBase + tid;
    if (node < n) {
        indptr[node] = base + excl;
        dinv[node] = rsqrtf((float)(v + 1));
    }
    ncnt[tid] = 0;
    __syncthreads();

    for (int j = tid; j < cntE; j += 256) {
        unsigned e = packed[pb + j];
        int c = (int)(e & 255u);
        int r = (int)(e >> 8);
        int p = nbase[c] + atomicAdd(&ncnt[c], 1);
        srow[p] = r;
    }
    __syncthreads();

    for (int j = tid; j < cntE; j += 256) srcidx[base + j] = srow[j];
}

// ---------------- weight prep + zero-row init ----------------
// Wt1; Wt2 k-permuted; b1 permuted (pi(p)=(p&7)*16+(p>>3)); zero rows n of D1q/D2; shifts[n]=0.
__global__ void k_wprep(const float* __restrict__ W1, const float* __restrict__ W2,
                        const float* __restrict__ b1,
                        unsigned short* __restrict__ Wt1, unsigned short* __restrict__ Wt2p,
                        float* __restrict__ b1p,
                        unsigned* __restrict__ D1qz,   // D1q row n (32 uints)
                        unsigned* __restrict__ D2z,    // D2 row n (32 uints)
                        unsigned char* __restrict__ shifts, int n) {
    int idx = blockIdx.x * blockDim.x + threadIdx.x;
    const int B0 = 128 * 128, B1 = B0 + 64 * 128, B2 = B1 + 128, B3 = B2 + 32, B4 = B3 + 32;
    if (idx < B0) {
        int colc = idx >> 7, k = idx & 127;
        Wt1[colc * 128 + k] = f2bf(W1[k * 128 + colc]);
    } else if (idx < B1) {
        int j = idx - B0;
        int colc = j >> 7, p = j & 127;
        int korig = (p & 7) * 16 + (p >> 3);
        Wt2p[colc * 128 + p] = f2bf(W2[korig * 64 + colc]);
    } else if (idx < B2) {
        int p = idx - B1;
        b1p[p] = b1[(p & 7) * 16 + (p >> 3)];
    } else if (idx < B3) {
        D1qz[idx - B2] = 0;
    } else if (idx < B4) {
        D2z[idx - B3] = 0;
    } else if (idx == B4) {
        shifts[n] = 0;
    }
}

// ---------------- gemm1: D1q = int8_pow2(dinv ⊙ (concat(x,cemb) @ W1t^T)) ----------------
// Column-PERMUTED storage (byte p=lr*8+cf = orig col cf*16+lr). Per-row pow2 scale:
// value = q * 2^(shift-16), shift in [0,15] stored in shifts[].
__global__ __launch_bounds__(256) void k_gemm1(const float* __restrict__ x,
                                               const int* __restrict__ cid,
                                               const float* __restrict__ cemb,
                                               const unsigned short* __restrict__ Wt,
                                               const float* __restrict__ dinv,
                                               unsigned char* __restrict__ D1q,
                                               unsigned char* __restrict__ shifts, int n) {
    int tid = threadIdx.x;
    int wid = tid >> 6, lane = tid & 63;
    int rbase = blockIdx.x * 64 + wid * 16;
    int lr = lane & 15, kq = lane >> 4;

    int arow = rbase + lr;
    if (arow > n - 1) arow = n - 1;
    const float* xp = x + (size_t)arow * 120 + kq * 8;

    bf16x8 a0 = cvt8(*(const float4*)(xp),      *(const float4*)(xp + 4));
    bf16x8 a1 = cvt8(*(const float4*)(xp + 32), *(const float4*)(xp + 36));
    bf16x8 a2 = cvt8(*(const float4*)(xp + 64), *(const float4*)(xp + 68));
    bf16x8 a3;
    if (kq < 3) {
        a3 = cvt8(*(const float4*)(xp + 96), *(const float4*)(xp + 100));
    } else {
        const float* cp = cemb + (size_t)cid[arow] * 8;
        a3 = cvt8(*(const float4*)(cp), *(const float4*)(cp + 4));
    }

    f32x4 acc[8];
#pragma unroll
    for (int cf = 0; cf < 8; ++cf) acc[cf] = (f32x4){0.f, 0.f, 0.f, 0.f};

#pragma unroll
    for (int cf = 0; cf < 8; ++cf) {
        const unsigned short* bp = Wt + (size_t)(cf * 16 + lr) * 128 + kq * 8;
        bf16x8 b0 = *(const bf16x8*)(bp);
        bf16x8 b1 = *(const bf16x8*)(bp + 32);
        bf16x8 b2 = *(const bf16x8*)(bp + 64);
        bf16x8 b3 = *(const bf16x8*)(bp + 96);
        acc[cf] = __builtin_amdgcn_mfma_f32_16x16x32_bf16(a0, b0, acc[cf], 0, 0, 0);
        acc[cf] = __builtin_amdgcn_mfma_f32_16x16x32_bf16(a1, b1, acc[cf], 0, 0, 0);
        acc[cf] = __builtin_amdgcn_mfma_f32_16x16x32_bf16(a2, b2, acc[cf], 0, 0, 0);
        acc[cf] = __builtin_amdgcn_mfma_f32_16x16x32_bf16(a3, b3, acc[cf], 0, 0, 0);
    }

#pragma unroll
    for (int r = 0; r < 4; ++r) {
        int grow = rbase + kq * 4 + r;
        float dv = (grow < n) ? dinv[grow] : 0.f;
        float m = 0.f;
#pragma unroll
        for (int cf = 0; cf < 8; ++cf) m = fmaxf(m, fabsf(acc[cf][r] * dv));
        m = fmaxf(m, __shfl_xor(m, 1));
        m = fmaxf(m, __shfl_xor(m, 2));
        m = fmaxf(m, __shfl_xor(m, 4));
        m = fmaxf(m, __shfl_xor(m, 8));
        // pow2 scale: s = 2^ee, ee = ceil(log2(m)) - 7, clamped to [-16, -1]
        int mb = (int)((__float_as_uint(m) >> 23) & 255u);
        int er = mb - 127 + 1 - 7;
        int sh = min(max(er + 16, 0), 15);
        int ee = sh - 16;
        float sinv = __uint_as_float((unsigned)(127 - ee) << 23);  // 2^-ee
        if (grow < n) {
            if (lr == 0) shifts[grow] = (unsigned char)sh;
            unsigned lo = 0, hi = 0;
#pragma unroll
            for (int cf = 0; cf < 4; ++cf) {
                int q8 = (int)rintf(acc[cf][r] * dv * sinv);
                q8 = min(max(q8, -127), 127);
                lo |= ((unsigned)(q8 & 255)) << (8 * cf);
            }
#pragma unroll
            for (int cf = 4; cf < 8; ++cf) {
                int q8 = (int)rintf(acc[cf][r] * dv * sinv);
                q8 = min(max(q8, -127), 127);
                hi |= ((unsigned)(q8 & 255)) << (8 * (cf - 4));
            }
            *(uint2*)&D1q[(size_t)grow * 128 + lr * 8] = make_uint2(lo, hi);
        }
    }
}

// ---------------- gemm2: D2 = dinv ⊙ (H1p[N,128] @ Wt2p^T), bf16 out ----------------
template <int NOUT>
__global__ __launch_bounds__(256) void k_gemm_bf16(const unsigned short* __restrict__ A,
                                                   const unsigned short* __restrict__ Wt,
                                                   const float* __restrict__ dinv,
                                                   unsigned short* __restrict__ D, int n) {
    constexpr int NCF = NOUT / 16;
    int tid = threadIdx.x;
    int wid = tid >> 6, lane = tid & 63;
    int rbase = blockIdx.x * 64 + wid * 16;
    int lr = lane & 15, kq = lane >> 4;

    int arow = rbase + lr;
    if (arow > n - 1) arow = n - 1;
    const unsigned short* ap = A + (size_t)arow * 128 + kq * 8;
    bf16x8 a0 = *(const bf16x8*)(ap);
    bf16x8 a1 = *(const bf16x8*)(ap + 32);
    bf16x8 a2 = *(const bf16x8*)(ap + 64);
    bf16x8 a3 = *(const bf16x8*)(ap + 96);

    f32x4 acc[NCF];
#pragma unroll
    for (int cf = 0; cf < NCF; ++cf) acc[cf] = (f32x4){0.f, 0.f, 0.f, 0.f};

#pragma unroll
    for (int cf = 0; cf < NCF; ++cf) {
        const unsigned short* bp = Wt + (size_t)(cf * 16 + lr) * 128 + kq * 8;
        bf16x8 b0 = *(const bf16x8*)(bp);
        bf16x8 b1 = *(const bf16x8*)(bp + 32);
        bf16x8 b2 = *(const bf16x8*)(bp + 64);
        bf16x8 b3 = *(const bf16x8*)(bp + 96);
        acc[cf] = __builtin_amdgcn_mfma_f32_16x16x32_bf16(a0, b0, acc[cf], 0, 0, 0);
        acc[cf] = __builtin_amdgcn_mfma_f32_16x16x32_bf16(a1, b1, acc[cf], 0, 0, 0);
        acc[cf] = __builtin_amdgcn_mfma_f32_16x16x32_bf16(a2, b2, acc[cf], 0, 0, 0);
        acc[cf] = __builtin_amdgcn_mfma_f32_16x16x32_bf16(a3, b3, acc[cf], 0, 0, 0);
    }

    float dv[4];
#pragma unroll
    for (int r = 0; r < 4; ++r) {
        int grow = rbase + kq * 4 + r;
        dv[r] = (grow < n) ? dinv[grow] : 0.f;
    }
#pragma unroll
    for (int cf = 0; cf < NCF; ++cf) {
#pragma unroll
        for (int r = 0; r < 4; ++r) {
            int grow = rbase + kq * 4 + r;
            if (grow < n) D[(size_t)grow * NOUT + cf * 16 + lr] = f2bf(acc[cf][r] * dv[r]);
        }
    }
}

// ---------------- agg1: 16 nodes/block (4/wave), int8 rows, pure int accumulate ---------
// H1p[i][p] = relu(dinv_i * 2^-16 * (sum_e q[src][p]<<sh_src + q[i][p]<<sh_i) + b1p[p])
__global__ __launch_bounds__(256) void k_agg1(const uint2* __restrict__ rows,   // D1q [n+1][16]
                                              const unsigned char* __restrict__ shifts,
                                              const int* __restrict__ indptr,
                                              const int* __restrict__ srcidx,
                                              const float* __restrict__ dinv,
                                              const float* __restrict__ b1p,
                                              uint4* __restrict__ Out, int n) {
    int tid = threadIdx.x;
    int lane = tid & 63;
    int g = lane >> 4, gl = lane & 15;
    int i = blockIdx.x * 16 + (tid >> 6) * 4 + g;
    if (i > n - 1) i = n - 1;

    float di = dinv[i];
    float4 bA = *(const float4*)&b1p[gl * 8];
    float4 bB = *(const float4*)&b1p[gl * 8 + 4];

    uint2 sq = rows[(size_t)i * 16 + gl];
    int ssh = shifts[i];
    int a[8];
#pragma unroll
    for (int j = 0; j < 4; ++j) {
        a[j]     = ((int)(signed char)((sq.x >> (8 * j)) & 255u)) << ssh;
        a[j + 4] = ((int)(signed char)((sq.y >> (8 * j)) & 255u)) << ssh;
    }

    int e0 = indptr[i];
    int d = indptr[i + 1] - e0;
    int m = max(d, __shfl_xor(d, 16));
    m = max(m, __shfl_xor(m, 32));

#pragma unroll 4
    for (int t = 0; t < m; ++t) {
        bool act = t < d;
        int s = act ? srcidx[e0 + t] : n;   // row n is all-zero, shifts[n]=0
        int sh = shifts[s];
        uint2 q = rows[(size_t)s * 16 + gl];
#pragma unroll
        for (int j = 0; j < 4; ++j) {
            a[j]     += ((int)(signed char)((q.x >> (8 * j)) & 255u)) << sh;
            a[j + 4] += ((int)(signed char)((q.y >> (8 * j)) & 255u)) << sh;
        }
    }

    float sc = di * 0x1p-16f;
    uint4 o;
    o.x = packbf(fmaxf((float)a[0] * sc + bA.x, 0.f), fmaxf((float)a[1] * sc + bA.y, 0.f));
    o.y = packbf(fmaxf((float)a[2] * sc + bA.z, 0.f), fmaxf((float)a[3] * sc + bA.w, 0.f));
    o.z = packbf(fmaxf((float)a[4] * sc + bB.x, 0.f), fmaxf((float)a[5] * sc + bB.y, 0.f));
    o.w = packbf(fmaxf((float)a[6] * sc + bB.z, 0.f), fmaxf((float)a[7] * sc + bB.w, 0.f));
    Out[(size_t)i * 16 + gl] = o;
}

// ---------------- agg2: 16 nodes/block (4/wave), bf16 rows, f32 out ----------------
__global__ __launch_bounds__(256) void k_agg2(const uint2* __restrict__ Hs,   // D2 [n+1][16]
                                              const int* __restrict__ indptr,
                                              const int* __restrict__ srcidx,
                                              const float* __restrict__ dinv,
                                              const float* __restrict__ bias,
                                              float4* __restrict__ Out, int n) {
    int tid = threadIdx.x;
    int lane = tid & 63;
    int g = lane >> 4, gl = lane & 15;
    int i = blockIdx.x * 16 + (tid >> 6) * 4 + g;
    if (i > n - 1) i = n - 1;

    float di = dinv[i];
    float4 b = *(const float4*)&bias[gl * 4];

    uint2 sv = Hs[(size_t)i * 16 + gl];
    float a0 = bfu_lo(sv.x), a1 = bfu_hi(sv.x);
    float a2 = bfu_lo(sv.y), a3 = bfu_hi(sv.y);

    int e0 = indptr[i];
    int d = indptr[i + 1] - e0;
    int m = max(d, __shfl_xor(d, 16));
    m = max(m, __shfl_xor(m, 32));

#pragma unroll 4
    for (int t = 0; t < m; ++t) {
        bool act = t < d;
        int s = act ? srcidx[e0 + t] : n;   // zero row
        uint2 w = Hs[(size_t)s * 16 + gl];
        a0 += bfu_lo(w.x);
        a1 += bfu_hi(w.x);
        a2 += bfu_lo(w.y);
        a3 += bfu_hi(w.y);
    }
    Out[(size_t)i * 16 + gl] = make_float4(di * a0 + b.x, di * a1 + b.y,
                                           di * a2 + b.z, di * a3 + b.w);
}

// ---------------- launch ----------------

extern "C" void kernel_launch(void* const* d_in, const int* in_sizes, int n_in,
                              void* d_out, int out_size, void* d_ws, size_t ws_size,
                              hipStream_t stream) {
    const float* x    = (const float*)d_in[0];
    const int*   eidx = (const int*)d_in[1];
    const int*   cid  = (const int*)d_in[2];
    const float* cemb = (const float*)d_in[3];
    const float* W1   = (const float*)d_in[4];
    const float* b1   = (const float*)d_in[5];
    const float* W2   = (const float*)d_in[6];
    const float* b2   = (const float*)d_in[7];
    float* out = (float*)d_out;

    int n = in_sizes[2];
    int E = in_sizes[1] / 2;
    const int* row = eidx;
    const int* col = eidx + E;
    int NB = (n + 255) / 256;

    char* ws = (char*)d_ws;
    auto alloc = [&](size_t bytes) {
        char* p = ws;
        ws += (bytes + 255) & ~(size_t)255;
        return p;
    };
    float*          dinv   = (float*)alloc((size_t)n * 4);
    int*            gcnt   = (int*)alloc((size_t)NB * 4);
    int*            gbase  = (int*)alloc((size_t)NB * 4);
    int*            indptr = (int*)alloc((size_t)(n + 1) * 4);
    int*            srcidx = (int*)alloc((size_t)E * 4);
    unsigned*       packed = (unsigned*)alloc((size_t)NB * CAPB * 4);
    unsigned short* Wt1    = (unsigned short*)alloc(128 * 128 * 2);
    unsigned short* Wt2p   = (unsigned short*)alloc(64 * 128 * 2);
    float*          b1p    = (float*)alloc(128 * 4);
    unsigned char*  D1q    = (unsigned char*)alloc((size_t)(n + 1) * 128);
    unsigned char*  shifts = (unsigned char*)alloc((size_t)(n + 1));
    unsigned short* H1p    = (unsigned short*)alloc((size_t)n * 128 * 2);
    unsigned short* D2     = (unsigned short*)alloc((size_t)(n + 1) * 64 * 2);

    // CSR build (bucketed two-pass, packed32)
    k_zero_int<<<(NB + 255) / 256, 256, 0, stream>>>(gcnt, NB);
    k_passA<<<(E + 4095) / 4096, 256, 0, stream>>>(row, col, gcnt, packed, E, NB);
    k_bscan<<<1, 512, 0, stream>>>(gcnt, gbase, indptr, n, E, NB);
    k_passB<<<NB, 256, 0, stream>>>(packed, gcnt, gbase, indptr, dinv, srcidx, n);

    // weight prep + zero-row init
    int wpn = 128 * 128 + 64 * 128 + 128 + 32 + 32 + 1;
    k_wprep<<<(wpn + 255) / 256, 256, 0, stream>>>(
        W1, W2, b1, Wt1, Wt2p, b1p,
        (unsigned*)(D1q + (size_t)n * 128),
        (unsigned*)(D2 + (size_t)n * 64),
        shifts, n);

    int gb = (n + 63) / 64;
    int ga = (n + 15) / 16;
    // layer 1
    k_gemm1<<<gb, 256, 0, stream>>>(x, cid, cemb, Wt1, dinv, D1q, shifts, n);
    k_agg1<<<ga, 256, 0, stream>>>((const uint2*)D1q, shifts, indptr, srcidx, dinv, b1p,
                                   (uint4*)H1p, n);
    // layer 2
    k_gemm_bf16<64><<<gb, 256, 0, stream>>>(H1p, Wt2p, dinv, D2, n);
    k_agg2<<<ga, 256, 0, stream>>>((const uint2*)D2, indptr, srcidx, dinv, b2,
                                   (float4*)out, n);
}